// Round 4
// baseline (88.657 us; speedup 1.0000x reference)
//
#include <hip/hip_runtime.h>

#define IMG 30
#define N3 (IMG * IMG * IMG)
#define THREADS 64
#define NBLK ((N3 + THREADS - 1) / THREADS)   // 422 blocks, 1 wave each

// d_ws layout: double acc[4] (A0,A1,B0,B1) at offset 0; unsigned cnt at offset 32.
// All zeroed by a 64-byte hipMemsetAsync before the kernel.
__global__ __launch_bounds__(THREADS) void sncut_fused(const float* __restrict__ img,
                                                       const float* __restrict__ e0,
                                                       double* __restrict__ acc,
                                                       unsigned* __restrict__ cnt,
                                                       float* __restrict__ out) {
    const int n = blockIdx.x * blockDim.x + threadIdx.x;

    double a0 = 0.0, a1 = 0.0, b0 = 0.0, b1 = 0.0;

    if (n < N3) {
        const int z = n % IMG;
        const int y = (n / IMG) % IMG;
        const int x = n / (IMG * IMG);

        const float c = img[n];
        const float e = e0[n];
        const float inv_oi2 = 1.0f / 121.0f;   // 1/OI^2

        // W2 over (dc, dm): exp(-(dc^2 + 2*dm^2)/OX^2), OX=3; nonzero only for
        // dc,dm in {-1,0,1} since dw2 = dc^2 + 2*dm^2 <= RADIUS=3.
        const float w_e1 = 0.89483931681f;   // exp(-1/9)
        const float w_e2 = 0.80073740292f;   // exp(-2/9)
        const float w_e3 = 0.71653131057f;   // exp(-3/9)
        const float W[3][3] = {
            { w_e3, w_e1, w_e3 },   // dc=-1: dw2 = 3, 1, 3
            { w_e2, 1.0f, w_e2 },   // dc= 0: dw2 = 2, 0, 2
            { w_e3, w_e1, w_e3 },   // dc=+1
        };

        float denIn = 0.0f;   // sum_in  w * pg
        float nom0  = 0.0f;   // sum_in  w * pg * e0[nb]
        float wOOB  = 0.0f;   // sum_oob w

        #pragma unroll
        for (int db = -3; db <= 3; ++db) {
            const int nx = x + db;
            const bool xin = (unsigned)nx < (unsigned)IMG;
            #pragma unroll
            for (int dc = -1; dc <= 1; ++dc) {
                const int ny = y + dc;
                const bool yin = (unsigned)ny < (unsigned)IMG;
                #pragma unroll
                for (int dm = -1; dm <= 1; ++dm) {
                    const int nz = z + dm;
                    const bool zin = (unsigned)nz < (unsigned)IMG;
                    const float w = W[dc + 1][dm + 1];
                    if (xin && yin && zin) {
                        const int idx = (nx * IMG + ny) * IMG + nz;
                        const float p = img[idx];
                        const float d = p - c;
                        const float pg = __expf(-d * d * inv_oi2);  // v_exp_f32 fast path
                        const float wpg = w * pg;
                        denIn += wpg;
                        nom0  += wpg * e0[idx];
                    } else {
                        wOOB += w;
                    }
                }
            }
        }

        const float pgc  = __expf(-c * c * inv_oi2);  // Pg of zero-padded entries
        const float den  = denIn + wOOB * pgc;        // OOB terms: den only (S=0 there)
        const float nom1 = denIn - nom0;              // second cluster numerator

        a0 = (double)(e * nom0);
        a1 = (double)((1.0f - e) * nom1);
        b0 = (double)(e * den);
        b1 = (double)((1.0f - e) * den);
    }

    // single-wave butterfly reduction
    #pragma unroll
    for (int off = 32; off > 0; off >>= 1) {
        a0 += __shfl_down(a0, off, 64);
        a1 += __shfl_down(a1, off, 64);
        b0 += __shfl_down(b0, off, 64);
        b1 += __shfl_down(b1, off, 64);
    }

    if (threadIdx.x == 0) {
        // device-scope atomics (cross-XCD safe per G12/G16)
        atomicAdd(&acc[0], a0);
        atomicAdd(&acc[1], a1);
        atomicAdd(&acc[2], b0);
        atomicAdd(&acc[3], b1);
        __threadfence();                       // order acc adds before cnt add
        const unsigned old = atomicAdd(cnt, 1u);
        if (old == NBLK - 1) {
            // last block: all 422 acc-adds are visible (fence + atomic ordering).
            // Read back via atomic fetch-add(0) to bypass any stale L1.
            const double A0 = atomicAdd(&acc[0], 0.0);
            const double A1 = atomicAdd(&acc[1], 0.0);
            const double B0 = atomicAdd(&acc[2], 0.0);
            const double B1 = atomicAdd(&acc[3], 0.0);
            // loss = mean(K_CLUST - (assoc0 + assoc1)); scalar mean = identity
            out[0] = (float)(2.0 - A0 / B0 - A1 / B1);
        }
    }
}

extern "C" void kernel_launch(void* const* d_in, const int* in_sizes, int n_in,
                              void* d_out, int out_size, void* d_ws, size_t ws_size,
                              hipStream_t stream) {
    const float* image = (const float*)d_in[0];  // (1,1,30,30,30) -> img = image[0,0]
    const float* enc   = (const float*)d_in[1];  // (1,2,30,30,30) -> e0 = enc[0,0]
    float* out = (float*)d_out;
    double* acc = (double*)d_ws;                           // 4 doubles
    unsigned* cnt = (unsigned*)((char*)d_ws + 32);         // arrival counter

    // zero acc + cnt (d_ws is poisoned 0xAA before every timed launch)
    hipMemsetAsync(d_ws, 0, 64, stream);

    sncut_fused<<<NBLK, THREADS, 0, stream>>>(image, enc, acc, cnt, out);
}

// Round 5
// 68.985 us; speedup vs baseline: 1.2852x; 1.2852x over previous
//
#include <hip/hip_runtime.h>

#define IMG 30
#define N3 (IMG * IMG * IMG)
#define THREADS 64
#define NBLK ((N3 + THREADS - 1) / THREADS)   // 422 blocks, 1 wave each

// d_ws layout: partial[4][NBLK] doubles (fully written every launch, no init needed)
__global__ __launch_bounds__(THREADS) void sncut_main(const float* __restrict__ img,
                                                      const float* __restrict__ e0,
                                                      double* __restrict__ partial) {
    const int n = blockIdx.x * blockDim.x + threadIdx.x;

    double a0 = 0.0, a1 = 0.0, b0 = 0.0, b1 = 0.0;

    if (n < N3) {
        const int z = n % IMG;
        const int y = (n / IMG) % IMG;
        const int x = n / (IMG * IMG);

        const float c = img[n];
        const float e = e0[n];
        const float inv_oi2 = 1.0f / 121.0f;   // 1/OI^2

        // W2 over (dc, dm): exp(-(dc^2 + 2*dm^2)/OX^2), OX=3; nonzero only for
        // dc,dm in {-1,0,1} since dw2 = dc^2 + 2*dm^2 <= RADIUS=3.
        const float w_e1 = 0.89483931681f;   // exp(-1/9)
        const float w_e2 = 0.80073740292f;   // exp(-2/9)
        const float w_e3 = 0.71653131057f;   // exp(-3/9)
        const float W[3][3] = {
            { w_e3, w_e1, w_e3 },   // dc=-1: dw2 = 3, 1, 3
            { w_e2, 1.0f, w_e2 },   // dc= 0: dw2 = 2, 0, 2
            { w_e3, w_e1, w_e3 },   // dc=+1
        };

        float denIn = 0.0f;   // sum_in  w * pg
        float nom0  = 0.0f;   // sum_in  w * pg * e0[nb]
        float wOOB  = 0.0f;   // sum_oob w

        #pragma unroll
        for (int db = -3; db <= 3; ++db) {
            const int nx = x + db;
            const bool xin = (unsigned)nx < (unsigned)IMG;
            #pragma unroll
            for (int dc = -1; dc <= 1; ++dc) {
                const int ny = y + dc;
                const bool yin = (unsigned)ny < (unsigned)IMG;
                #pragma unroll
                for (int dm = -1; dm <= 1; ++dm) {
                    const int nz = z + dm;
                    const bool zin = (unsigned)nz < (unsigned)IMG;
                    const float w = W[dc + 1][dm + 1];
                    if (xin && yin && zin) {
                        const int idx = (nx * IMG + ny) * IMG + nz;
                        const float p = img[idx];
                        const float d = p - c;
                        const float pg = __expf(-d * d * inv_oi2);  // v_exp_f32 fast path
                        const float wpg = w * pg;
                        denIn += wpg;
                        nom0  += wpg * e0[idx];
                    } else {
                        wOOB += w;
                    }
                }
            }
        }

        const float pgc  = __expf(-c * c * inv_oi2);  // Pg of zero-padded entries
        const float den  = denIn + wOOB * pgc;        // OOB terms: den only (S=0 there)
        const float nom1 = denIn - nom0;              // second cluster numerator

        a0 = (double)(e * nom0);
        a1 = (double)((1.0f - e) * nom1);
        b0 = (double)(e * den);
        b1 = (double)((1.0f - e) * den);
    }

    // single-wave butterfly reduction
    #pragma unroll
    for (int off = 32; off > 0; off >>= 1) {
        a0 += __shfl_down(a0, off, 64);
        a1 += __shfl_down(a1, off, 64);
        b0 += __shfl_down(b0, off, 64);
        b1 += __shfl_down(b1, off, 64);
    }
    if (threadIdx.x == 0) {
        partial[0 * NBLK + blockIdx.x] = a0;
        partial[1 * NBLK + blockIdx.x] = a1;
        partial[2 * NBLK + blockIdx.x] = b0;
        partial[3 * NBLK + blockIdx.x] = b1;
    }
}

__global__ __launch_bounds__(THREADS) void sncut_final(const double* __restrict__ partial,
                                                       float* __restrict__ out) {
    double a0 = 0.0, a1 = 0.0, b0 = 0.0, b1 = 0.0;
    for (int i = threadIdx.x; i < NBLK; i += THREADS) {
        a0 += partial[0 * NBLK + i];
        a1 += partial[1 * NBLK + i];
        b0 += partial[2 * NBLK + i];
        b1 += partial[3 * NBLK + i];
    }
    #pragma unroll
    for (int off = 32; off > 0; off >>= 1) {
        a0 += __shfl_down(a0, off, 64);
        a1 += __shfl_down(a1, off, 64);
        b0 += __shfl_down(b0, off, 64);
        b1 += __shfl_down(b1, off, 64);
    }
    if (threadIdx.x == 0) {
        // loss = mean(K_CLUST - (assoc0 + assoc1)); mean of a scalar is identity
        out[0] = (float)(2.0 - a0 / b0 - a1 / b1);
    }
}

extern "C" void kernel_launch(void* const* d_in, const int* in_sizes, int n_in,
                              void* d_out, int out_size, void* d_ws, size_t ws_size,
                              hipStream_t stream) {
    const float* image = (const float*)d_in[0];  // (1,1,30,30,30) -> img = image[0,0]
    const float* enc   = (const float*)d_in[1];  // (1,2,30,30,30) -> e0 = enc[0,0]
    float* out = (float*)d_out;
    double* partial = (double*)d_ws;             // 4*NBLK doubles = 13.5 KB

    sncut_main<<<NBLK, THREADS, 0, stream>>>(image, enc, partial);
    sncut_final<<<1, THREADS, 0, stream>>>(partial, out);
}